// Round 9
// baseline (47.447 us; speedup 1.0000x reference)
//
#include <hip/hip_runtime.h>

#define D_MODEL 1024
#define N_MOD   4
#define EB      32     // e-chunks
#define ECHUNK  32     // e per chunk
#define EPW     8      // e per esub-wave

typedef float fx4 __attribute__((ext_vector_type(4)));

// ============ Stage (fused): partials + last-block reduce ============
// Grid (EB=32, DC=4) = 128 blocks. Block (eb,dc) computes partial[m][eb][dc-slice].
// The 32nd block to finish within each dc (ticket mod 32 == 31; works for any
// persistent counter start value, no reset needed) reduces over eb -> Weff.
__global__ __launch_bounds__(256) void weff_stage_kernel(
    const fx4*   __restrict__ Wg4,      // [1024][256] fx4
    const float* __restrict__ Wr,       // [4][1024]
    fx4*         __restrict__ partial4, // [4][EB][256] fx4
    fx4*         __restrict__ Weff4,    // [4][256] fx4
    unsigned*    __restrict__ counters) // [4]
{
    const int t    = threadIdx.x;
    const int esub = t >> 6;
    const int d4   = t & 63;
    const int eb   = blockIdx.x;
    const int dc   = blockIdx.y;
    const int d4g  = dc * 64 + d4;
    const int e0   = eb * ECHUNK + esub * EPW;

    fx4 acc[N_MOD];
    #pragma unroll
    for (int m = 0; m < N_MOD; ++m) acc[m] = (fx4)(0.f);
    #pragma unroll
    for (int k = 0; k < EPW; ++k) {
        const int e = e0 + k;
        const fx4 wg = Wg4[e * 256 + d4g];
        #pragma unroll
        for (int m = 0; m < N_MOD; ++m)
            acc[m] += Wr[m * D_MODEL + e] * wg;   // wave-uniform scalar Wr load
    }
    __shared__ fx4 red[4][N_MOD][64];
    #pragma unroll
    for (int m = 0; m < N_MOD; ++m) red[esub][m][d4] = acc[m];
    __syncthreads();
    const int m2 = t >> 6;
    partial4[(m2 * EB + eb) * 256 + d4g] =
        red[0][m2][d4] + red[1][m2][d4] + red[2][m2][d4] + red[3][m2][d4];

    // ---- last-block reduction for this dc ----
    __threadfence();                       // release partial stores (device scope)
    __syncthreads();
    __shared__ unsigned tick;
    if (t == 0) tick = atomicAdd(&counters[dc], 1u);
    __syncthreads();
    if ((tick & 31u) == 31u) {             // 32nd taker this launch = last block
        __threadfence();                   // acquire
        fx4 s = (fx4)(0.f);
        #pragma unroll
        for (int eb2 = 0; eb2 < EB; ++eb2)
            s += partial4[(m2 * EB + eb2) * 256 + d4g];  // 1KB coalesced per eb2
        Weff4[m2 * 256 + d4g] = s;
    }
}

// ============ Main v3: phase-split (stream 8 rows, then 8 ILP reduce chains) ====
__global__ __launch_bounds__(256) void router_main_kernel(
    const float* __restrict__ h,     // [B, 1024]
    const float* __restrict__ Weff,  // [4, 1024]
    float* __restrict__ out,         // [4][B][4]
    int B)
{
    const int lane = threadIdx.x & 63;
    const int wave = threadIdx.x >> 6;

    fx4 w4[N_MOD][4];
    const fx4* __restrict__ W4 = (const fx4*)Weff;
    #pragma unroll
    for (int m = 0; m < N_MOD; ++m)
        #pragma unroll
        for (int c = 0; c < 4; ++c)
            w4[m][c] = W4[m * 256 + c * 64 + lane];

    float4* __restrict__ out4 = (float4*)out;   // [4][B] float4s
    const int wid  = blockIdx.x * 4 + wave;
    const int row0 = wid * 8;
    if (row0 >= B) return;

    const fx4* __restrict__ hb = (const fx4*)(h + (size_t)row0 * D_MODEL);

    float acc[8][N_MOD];
    #pragma unroll
    for (int i = 0; i < 8; ++i)
        #pragma unroll
        for (int m = 0; m < N_MOD; ++m) acc[i][m] = 0.f;

    fx4 va[4], vb[4];

#define LOADV(dst, ri)                                             \
    { const fx4* hp = hb + (ri) * 256;                             \
      dst[0] = hp[0 * 64 + lane]; dst[1] = hp[1 * 64 + lane];      \
      dst[2] = hp[2 * 64 + lane]; dst[3] = hp[3 * 64 + lane]; }

#define FMAV(src, i)                                               \
    { _Pragma("unroll")                                            \
      for (int c = 0; c < 4; ++c) {                                \
        _Pragma("unroll")                                          \
        for (int m = 0; m < N_MOD; ++m) {                          \
          acc[i][m] = fmaf(src[c].x, w4[m][c].x, acc[i][m]);       \
          acc[i][m] = fmaf(src[c].y, w4[m][c].y, acc[i][m]);       \
          acc[i][m] = fmaf(src[c].z, w4[m][c].z, acc[i][m]);       \
          acc[i][m] = fmaf(src[c].w, w4[m][c].w, acc[i][m]);       \
        } } }

    // Phase A: pure streaming, 1-row-ahead double buffer, no cross-lane ops.
    LOADV(va, 0);
    LOADV(vb, 1); FMAV(va, 0);
    LOADV(va, 2); FMAV(vb, 1);
    LOADV(vb, 3); FMAV(va, 2);
    LOADV(va, 4); FMAV(vb, 3);
    LOADV(vb, 5); FMAV(va, 4);
    LOADV(va, 6); FMAV(vb, 5);
    LOADV(vb, 7); FMAV(va, 6);
    FMAV(vb, 7);
#undef LOADV
#undef FMAV

    // Phase B: 8 independent fold+butterfly+softmax chains (ILP hides latency).
    unsigned mask = 0;
    #pragma unroll
    for (int i = 0; i < 8; ++i) {
        const bool b0 = lane & 1;
        const float aa = (b0 ? acc[i][1] : acc[i][0])
                       + __shfl_xor(b0 ? acc[i][0] : acc[i][1], 1, 64);
        const float cc = (b0 ? acc[i][3] : acc[i][2])
                       + __shfl_xor(b0 ? acc[i][2] : acc[i][3], 1, 64);
        const bool b1 = lane & 2;
        float r = (b1 ? cc : aa) + __shfl_xor(b1 ? aa : cc, 2, 64);
        r += __shfl_xor(r, 4, 64);
        r += __shfl_xor(r, 8, 64);
        r += __shfl_xor(r, 16, 64);
        r += __shfl_xor(r, 32, 64);
        // r = logit of module lane&3, replicated across each 4-lane group
        float mx = fmaxf(r, __shfl_xor(r, 1, 64));
        mx = fmaxf(mx, __shfl_xor(mx, 2, 64));
        const float ex = expf(r - mx);        // argmax lane: exactly 1.0
        float S = ex + __shfl_xor(ex, 1, 64);
        S += __shfl_xor(S, 2, 64);
        // prob_m > 0.5  <=>  m == argmax  &&  S < 2   (ties -> S>=2 -> false)
        const bool hi = (r == mx) && (S < 2.0f);
        mask |= (hi ? 1u : 0u) << i;
    }

    // lanes 0-31 write 4 full 128B lines: module m = l>>3, row offset l&7
    const int m  = lane >> 3;
    const int rs = lane & 7;
    const unsigned mm = __shfl(mask, m, 64);  // lane m holds module m's mask
    if (lane < 32 && row0 + rs < B) {
        const bool hi = (mm >> rs) & 1;
        const float4 val = hi ? make_float4(0.5f, 0.5f, 0.f, 0.f)
                              : make_float4(1.f, 0.f, 0.f, 0.f);
        out4[(size_t)m * B + row0 + rs] = val;
    }
}

extern "C" void kernel_launch(void* const* d_in, const int* in_sizes, int n_in,
                              void* d_out, int out_size, void* d_ws, size_t ws_size,
                              hipStream_t stream) {
    const float* h  = (const float*)d_in[0];   // [B, 1024]
    const fx4*   Wg = (const fx4*)d_in[1];     // [1024, 1024] floats
    const float* Wr = (const float*)d_in[2];   // [4, 1024]
    float* out = (float*)d_out;                // [4][B][4]

    const int B = in_sizes[0] / D_MODEL;       // 32768

    float*    Weff     = (float*)d_ws;                              // 16 KB
    fx4*      partial  = (fx4*)((float*)d_ws + N_MOD * D_MODEL);    // 512 KB
    unsigned* counters = (unsigned*)((char*)d_ws + 16 * 1024 + 512 * 1024);

    dim3 g1(EB, 4);
    weff_stage_kernel<<<g1, 256, 0, stream>>>(Wg, Wr, partial, (fx4*)Weff,
                                              counters);

    const int grid = (B + 8 * 4 - 1) / (8 * 4); // 1024 for B=32768
    router_main_kernel<<<grid, 256, 0, stream>>>(h, Weff, out, B);
}

// Round 10
// 42.681 us; speedup vs baseline: 1.1117x; 1.1117x over previous
//
#include <hip/hip_runtime.h>

#define D_MODEL 1024
#define N_MOD   4
#define EB      32     // e-chunks
#define ECHUNK  32     // e per chunk
#define EPW     8      // e per esub-wave

typedef float fx4 __attribute__((ext_vector_type(4)));

// ============ Stage (fused, R9-proven): partials + last-block reduce ============
// Grid (EB=32, DC=4) = 128 blocks. Block (eb,dc) computes partial[m][eb][dc-slice].
// The 32nd ticket-taker within each dc (mod 32 == 31; works for any persistent
// counter value, no reset needed) reduces over eb -> Weff. Deterministic: the
// reduction is done by exactly one block, in a fixed summation order.
__global__ __launch_bounds__(256) void weff_stage_kernel(
    const fx4*   __restrict__ Wg4,      // [1024][256] fx4
    const float* __restrict__ Wr,       // [4][1024]
    fx4*         __restrict__ partial4, // [4][EB][256] fx4
    fx4*         __restrict__ Weff4,    // [4][256] fx4
    unsigned*    __restrict__ counters) // [4]
{
    const int t    = threadIdx.x;
    const int esub = t >> 6;
    const int d4   = t & 63;
    const int eb   = blockIdx.x;
    const int dc   = blockIdx.y;
    const int d4g  = dc * 64 + d4;
    const int e0   = eb * ECHUNK + esub * EPW;

    fx4 acc[N_MOD];
    #pragma unroll
    for (int m = 0; m < N_MOD; ++m) acc[m] = (fx4)(0.f);
    #pragma unroll
    for (int k = 0; k < EPW; ++k) {
        const int e = e0 + k;
        const fx4 wg = Wg4[e * 256 + d4g];
        #pragma unroll
        for (int m = 0; m < N_MOD; ++m)
            acc[m] += Wr[m * D_MODEL + e] * wg;   // wave-uniform scalar Wr load
    }
    __shared__ fx4 red[4][N_MOD][64];
    #pragma unroll
    for (int m = 0; m < N_MOD; ++m) red[esub][m][d4] = acc[m];
    __syncthreads();
    const int m2 = t >> 6;
    partial4[(m2 * EB + eb) * 256 + d4g] =
        red[0][m2][d4] + red[1][m2][d4] + red[2][m2][d4] + red[3][m2][d4];

    __threadfence();                       // release partial stores (device scope)
    __syncthreads();
    __shared__ unsigned tick;
    if (t == 0) tick = atomicAdd(&counters[dc], 1u);
    __syncthreads();
    if ((tick & 31u) == 31u) {             // last finisher for this dc
        __threadfence();                   // acquire
        fx4 s = (fx4)(0.f);
        #pragma unroll
        for (int eb2 = 0; eb2 < EB; ++eb2)
            s += partial4[(m2 * EB + eb2) * 256 + d4g];
        Weff4[m2 * 256 + d4g] = s;
    }
}

// ============ Main (R8-proven): 8 rows/wave, folded reduce, full-line stores ====
__global__ __launch_bounds__(256) void router_main_kernel(
    const float* __restrict__ h,     // [B, 1024]
    const float* __restrict__ Weff,  // [4, 1024]
    float* __restrict__ out,         // [4][B][4]
    int B)
{
    const int lane = threadIdx.x & 63;
    const int wave = threadIdx.x >> 6;

    fx4 w4[N_MOD][4];
    const fx4* __restrict__ W4 = (const fx4*)Weff;
    #pragma unroll
    for (int m = 0; m < N_MOD; ++m)
        #pragma unroll
        for (int c = 0; c < 4; ++c)
            w4[m][c] = W4[m * 256 + c * 64 + lane];

    float4* __restrict__ out4 = (float4*)out;   // [4][B] float4s
    const int wid  = blockIdx.x * 4 + wave;
    const int step = gridDim.x * 4 * 8;

    for (int row0 = wid * 8; row0 < B; row0 += step) {
        unsigned mask = 0;
        #pragma unroll
        for (int i = 0; i < 8; ++i) {
            const int row = row0 + i;
            const fx4* __restrict__ h4 = (const fx4*)(h + (size_t)row * D_MODEL);
            fx4 v[4];
            #pragma unroll
            for (int c = 0; c < 4; ++c) v[c] = h4[c * 64 + lane];

            float acc[N_MOD] = {0.f, 0.f, 0.f, 0.f};
            #pragma unroll
            for (int c = 0; c < 4; ++c) {
                #pragma unroll
                for (int m = 0; m < N_MOD; ++m) {
                    acc[m] = fmaf(v[c].x, w4[m][c].x, acc[m]);
                    acc[m] = fmaf(v[c].y, w4[m][c].y, acc[m]);
                    acc[m] = fmaf(v[c].z, w4[m][c].z, acc[m]);
                    acc[m] = fmaf(v[c].w, w4[m][c].w, acc[m]);
                }
            }
            // Fold 4 streams into lane%4, then butterfly: 7 shuffles total.
            const bool b0 = lane & 1;
            float a  = (b0 ? acc[1] : acc[0]) + __shfl_xor(b0 ? acc[0] : acc[1], 1, 64);
            float cc = (b0 ? acc[3] : acc[2]) + __shfl_xor(b0 ? acc[2] : acc[3], 1, 64);
            const bool b1 = lane & 2;
            float r  = (b1 ? cc : a) + __shfl_xor(b1 ? a : cc, 2, 64);
            r += __shfl_xor(r, 4, 64);
            r += __shfl_xor(r, 8, 64);
            r += __shfl_xor(r, 16, 64);
            r += __shfl_xor(r, 32, 64);
            // r = logit of module lane&3 (replicated across each 4-lane group)
            float mx = fmaxf(r, __shfl_xor(r, 1, 64));
            mx = fmaxf(mx, __shfl_xor(mx, 2, 64));
            const float ex = expf(r - mx);       // argmax lane: exactly 1.0
            float S = ex + __shfl_xor(ex, 1, 64);
            S = S + __shfl_xor(S, 2, 64);
            // prob_m > 0.5  <=>  m == argmax  &&  S < 2
            const bool hi = (r == mx) && (S < 2.0f);
            mask |= (hi ? 1u : 0u) << i;
        }
        // lanes 0-31 write 4 full 128B lines: module m = l>>3, row offset l&7
        const int m = lane >> 3;
        const int rs = lane & 7;
        const unsigned mm = __shfl(mask, m, 64); // lane m holds module m's mask
        if (lane < 32) {
            const bool hi = (mm >> rs) & 1;
            const float4 val = hi ? make_float4(0.5f, 0.5f, 0.f, 0.f)
                                  : make_float4(1.f, 0.f, 0.f, 0.f);
            out4[(size_t)m * B + row0 + rs] = val;
        }
    }
}

extern "C" void kernel_launch(void* const* d_in, const int* in_sizes, int n_in,
                              void* d_out, int out_size, void* d_ws, size_t ws_size,
                              hipStream_t stream) {
    const float* h  = (const float*)d_in[0];   // [B, 1024]
    const fx4*   Wg = (const fx4*)d_in[1];     // [1024, 1024] floats
    const float* Wr = (const float*)d_in[2];   // [4, 1024]
    float* out = (float*)d_out;                // [4][B][4]

    const int B = in_sizes[0] / D_MODEL;       // 32768

    float*    Weff     = (float*)d_ws;                              // 16 KB
    fx4*      partial  = (fx4*)((float*)d_ws + N_MOD * D_MODEL);    // 512 KB
    unsigned* counters = (unsigned*)((char*)d_ws + 16 * 1024 + 512 * 1024);

    dim3 g1(EB, 4);
    weff_stage_kernel<<<g1, 256, 0, stream>>>(Wg, Wr, partial, (fx4*)Weff,
                                              counters);

    const int grid = (B + 8 * 4 - 1) / (8 * 4); // 1024 for B=32768
    router_main_kernel<<<grid, 256, 0, stream>>>(h, Weff, out, B);
}